// Round 2
// baseline (14598.811 us; speedup 1.0000x reference)
//
#include <hip/hip_runtime.h>
#include <stdint.h>

// Problem constants (fixed by reference): B=32, T=512, d=1024, Kcb=256
#define NB    32
#define NT    512
#define ND    1024
#define NG    3072      // 3*d
#define NROW  16384     // B*T
#define KCB   256

typedef float  f32x4 __attribute__((ext_vector_type(4)));
typedef short  s16x8 __attribute__((ext_vector_type(8)));

// ---------------- bf16 helpers (hi/lo split precision) ----------------
__device__ __forceinline__ unsigned short f32_to_bf16(float x) {
    union { float f; unsigned int u; } v; v.f = x;
    unsigned int u = v.u;
    return (unsigned short)((u + 0x7FFFu + ((u >> 16) & 1u)) >> 16);
}
__device__ __forceinline__ float bf16_to_f32(unsigned short h) {
    union { float f; unsigned int u; } v; v.u = ((unsigned int)h) << 16; return v.f;
}

// ---------------- W_hh -> bf16 hi/lo split (once per launch) ----------------
__global__ __launch_bounds__(256) void prep_w(const float* __restrict__ W,
                                              unsigned short* __restrict__ Whi,
                                              unsigned short* __restrict__ Wlo) {
    int i = blockIdx.x * 256 + threadIdx.x;   // grid sized exactly: 3072*1024/256
    float w = W[i];
    unsigned short hi = f32_to_bf16(w);
    float rem = w - bf16_to_f32(hi);
    Whi[i] = hi;
    Wlo[i] = f32_to_bf16(rem);
}

// ---------------- quantize: fp64 scores, argmin, copy row, SSD ----------------
// 2048 blocks x 256 thr; each block handles 8 rows; thread = one codebook entry.
__global__ __launch_bounds__(256) void quantize_kernel(
    const float* __restrict__ feat, const float* __restrict__ cb,
    float* __restrict__ out_q, float* __restrict__ out_idx,
    int* __restrict__ idxi, float* __restrict__ acc)
{
    __shared__ float  fr[8][1024];     // 32 KB
    __shared__ double wsco[4];
    __shared__ int    wid[4];
    __shared__ int    winner;
    __shared__ float  sp[4];

    int tid = threadIdx.x;
    int r0  = blockIdx.x * 8;

    // stage 8 feature rows (coalesced float4)
    for (int i = 0; i < 8; ++i) {
        int g   = i * 256 + tid;       // 2048 float4 total; 256 f4 per row
        int row = g >> 8;
        int kq  = g & 255;
        float4 v = ((const float4*)(feat + (long)(r0 + row) * ND))[kq];
        ((float4*)&fr[row][0])[kq] = v;
    }
    __syncthreads();

    // fp64-accumulated dot(f_row, cb_tid) for 8 rows + |cb_tid|^2
    double dot[8];
    #pragma unroll
    for (int r = 0; r < 8; ++r) dot[r] = 0.0;
    double cc = 0.0;
    const float4* cbrow = (const float4*)(cb + (long)tid * ND);
    for (int k4 = 0; k4 < 256; ++k4) {
        float4 c = cbrow[k4];
        cc += (double)c.x * (double)c.x + (double)c.y * (double)c.y
            + (double)c.z * (double)c.z + (double)c.w * (double)c.w;
        #pragma unroll
        for (int r = 0; r < 8; ++r) {
            float4 f = ((const float4*)&fr[r][0])[k4];   // LDS broadcast
            dot[r] += (double)(f.x * c.x) + (double)(f.y * c.y)
                    + (double)(f.z * c.z) + (double)(f.w * c.w);
        }
    }

    float ssd_thread = 0.f;
    for (int r = 0; r < 8; ++r) {
        // argmin over cc - 2*dot (|f|^2 constant per row); first-index tie-break
        double s = cc - 2.0 * dot[r];
        int idx = tid;
        #pragma unroll
        for (int m = 1; m < 64; m <<= 1) {
            double s2 = __shfl_xor(s, m, 64);
            int    i2 = __shfl_xor(idx, m, 64);
            if (s2 < s || (s2 == s && i2 < idx)) { s = s2; idx = i2; }
        }
        int w = tid >> 6;
        if ((tid & 63) == 0) { wsco[w] = s; wid[w] = idx; }
        __syncthreads();
        if (tid == 0) {
            double bs = wsco[0]; int bi = wid[0];
            for (int w2 = 1; w2 < 4; ++w2)
                if (wsco[w2] < bs || (wsco[w2] == bs && wid[w2] < bi)) { bs = wsco[w2]; bi = wid[w2]; }
            winner = bi;
            out_idx[r0 + r] = (float)bi;    // indices as float (harness reads f32)
            idxi[r0 + r]    = bi;           // int copy for GRU gate lookup
        }
        __syncthreads();
        int win = winner;
        // copy codebook[win] into quantized output, accumulate SSD
        float4 q = ((const float4*)(cb + (long)win * ND))[tid];
        ((float4*)(out_q + (long)(r0 + r) * ND))[tid] = q;
        float4 f = ((const float4*)&fr[r][0])[tid];
        float dx = f.x - q.x, dy = f.y - q.y, dz = f.z - q.z, dw = f.w - q.w;
        ssd_thread += dx * dx + dy * dy + dz * dz + dw * dw;
        __syncthreads();
    }

    // block-reduce SSD, one atomic
    #pragma unroll
    for (int m = 1; m < 64; m <<= 1) ssd_thread += __shfl_xor(ssd_thread, m, 64);
    if ((tid & 63) == 0) sp[tid >> 6] = ssd_thread;
    __syncthreads();
    if (tid == 0) atomicAdd(&acc[33], sp[0] + sp[1] + sp[2] + sp[3]);
}

// ---------------- fp32 tiled GEMM: C[M,N] = A[M,K] * W[N,K]^T + bias[N] ----------------
// 128x128 block tile, BK=16, 256 thr, 8x8 register tile. K,N mult of 16/128; M mult of 128.
__global__ __launch_bounds__(256) void gemm_nt(
    const float* __restrict__ A, const float* __restrict__ W,
    const float* __restrict__ bias, float* __restrict__ C, int N, int K)
{
    __shared__ float As[16][132];
    __shared__ float Bs[16][132];
    int tid = threadIdx.x;
    int m0 = blockIdx.y * 128;
    int n0 = blockIdx.x * 128;
    int tx = tid & 15, ty = tid >> 4;

    float accum[8][8];
    #pragma unroll
    for (int i = 0; i < 8; ++i)
        #pragma unroll
        for (int j = 0; j < 8; ++j) accum[i][j] = 0.f;

    for (int k0 = 0; k0 < K; k0 += 16) {
        #pragma unroll
        for (int i = 0; i < 2; ++i) {
            int f   = tid + i * 256;   // 512 float4 per matrix tile
            int row = f >> 2;
            int kq  = f & 3;
            float4 a = *(const float4*)(A + (long)(m0 + row) * K + k0 + kq * 4);
            As[kq * 4 + 0][row] = a.x; As[kq * 4 + 1][row] = a.y;
            As[kq * 4 + 2][row] = a.z; As[kq * 4 + 3][row] = a.w;
            float4 b = *(const float4*)(W + (long)(n0 + row) * K + k0 + kq * 4);
            Bs[kq * 4 + 0][row] = b.x; Bs[kq * 4 + 1][row] = b.y;
            Bs[kq * 4 + 2][row] = b.z; Bs[kq * 4 + 3][row] = b.w;
        }
        __syncthreads();
        #pragma unroll
        for (int kk = 0; kk < 16; ++kk) {
            float4 a01 = *(const float4*)&As[kk][ty * 8];
            float4 a23 = *(const float4*)&As[kk][ty * 8 + 4];
            float4 b01 = *(const float4*)&Bs[kk][tx * 8];
            float4 b23 = *(const float4*)&Bs[kk][tx * 8 + 4];
            float av[8] = {a01.x, a01.y, a01.z, a01.w, a23.x, a23.y, a23.z, a23.w};
            float bv[8] = {b01.x, b01.y, b01.z, b01.w, b23.x, b23.y, b23.z, b23.w};
            #pragma unroll
            for (int i = 0; i < 8; ++i)
                #pragma unroll
                for (int j = 0; j < 8; ++j) accum[i][j] += av[i] * bv[j];
        }
        __syncthreads();
    }
    #pragma unroll
    for (int i = 0; i < 8; ++i) {
        float* crow = C + (long)(m0 + ty * 8 + i) * N + n0 + tx * 8;
        const float* brow = bias + n0 + tx * 8;
        float4 o0, o1;
        o0.x = accum[i][0] + brow[0]; o0.y = accum[i][1] + brow[1];
        o0.z = accum[i][2] + brow[2]; o0.w = accum[i][3] + brow[3];
        o1.x = accum[i][4] + brow[4]; o1.y = accum[i][5] + brow[5];
        o1.z = accum[i][6] + brow[6]; o1.w = accum[i][7] + brow[7];
        *(float4*)(crow)     = o0;
        *(float4*)(crow + 4) = o1;
    }
}

// ---------------- GRU step: MFMA bf16 hi/lo split, gates fused in registers ----------------
// grid 64 blocks (16 j-cols each => N-tiles {j,1024+j,2048+j}), 256 thr = 4 waves (k-split).
// gi comes from the 256x3072 code table GIcb indexed by idxi[b*T+t] (gi has only 256
// distinct rows since quantized rows are codebook entries).
__global__ __launch_bounds__(256) void gru_step(
    float* hs,                                  // [B][T][D], reads t-1, writes t
    const unsigned short* __restrict__ Whi, const unsigned short* __restrict__ Wlo,
    const float* __restrict__ GIcb,             // [256][3072] = cb@W_ih^T + b_ih
    const int* __restrict__ idxi,               // [B][T]
    const float* __restrict__ b_hh, int t)
{
    __shared__ unsigned short hhi[32][264];     // 32x256 chunk, stride-pad to 264
    __shared__ unsigned short hlo[32][264];
    __shared__ float red[4][64][25];            // k-split partial accumulators (pad 25)

    int tid  = threadIdx.x;
    int lane = tid & 63;
    int w    = tid >> 6;
    int jb   = blockIdx.x * 16;
    int m    = lane & 15, q = lane >> 4;

    f32x4 accv[2][3];
    #pragma unroll
    for (int mt = 0; mt < 2; ++mt)
        #pragma unroll
        for (int s = 0; s < 3; ++s) accv[mt][s] = (f32x4){0.f, 0.f, 0.f, 0.f};

    for (int c = 0; c < 4; ++c) {
        // stage h_prev chunk (cols [c*256, c*256+256)) as bf16 hi/lo
        for (int i = 0; i < 8; ++i) {
            int g = i * 256 + tid;     // 2048 float4
            int b = g >> 6, kq = g & 63;
            float4 v;
            if (t > 0) v = *(const float4*)(hs + (long)(b * NT + (t - 1)) * ND + c * 256 + kq * 4);
            else       v = make_float4(0.f, 0.f, 0.f, 0.f);
            ushort4 h4, l4;
            h4.x = f32_to_bf16(v.x); l4.x = f32_to_bf16(v.x - bf16_to_f32(h4.x));
            h4.y = f32_to_bf16(v.y); l4.y = f32_to_bf16(v.y - bf16_to_f32(h4.y));
            h4.z = f32_to_bf16(v.z); l4.z = f32_to_bf16(v.z - bf16_to_f32(h4.z));
            h4.w = f32_to_bf16(v.w); l4.w = f32_to_bf16(v.w - bf16_to_f32(h4.w));
            *(ushort4*)&hhi[b][kq * 4] = h4;
            *(ushort4*)&hlo[b][kq * 4] = l4;
        }
        __syncthreads();
        // wave w handles ksteps {2w, 2w+1} of this chunk (k-split across waves)
        #pragma unroll
        for (int kkl = 0; kkl < 2; ++kkl) {
            int kk    = w * 2 + kkl;
            int koff  = kk * 32 + q * 8;
            int kglob = c * 256 + koff;
            s16x8 ahi0 = *(const s16x8*)&hhi[m][koff];
            s16x8 alo0 = *(const s16x8*)&hlo[m][koff];
            s16x8 ahi1 = *(const s16x8*)&hhi[m + 16][koff];
            s16x8 alo1 = *(const s16x8*)&hlo[m + 16][koff];
            #pragma unroll
            for (int s = 0; s < 3; ++s) {
                long wrow = (long)(s * ND + jb + m) * ND + kglob;
                s16x8 bhi = *(const s16x8*)(Whi + wrow);
                s16x8 blo = *(const s16x8*)(Wlo + wrow);
                accv[0][s] = __builtin_amdgcn_mfma_f32_16x16x32_bf16(ahi0, bhi, accv[0][s], 0, 0, 0);
                accv[0][s] = __builtin_amdgcn_mfma_f32_16x16x32_bf16(ahi0, blo, accv[0][s], 0, 0, 0);
                accv[0][s] = __builtin_amdgcn_mfma_f32_16x16x32_bf16(alo0, bhi, accv[0][s], 0, 0, 0);
                accv[1][s] = __builtin_amdgcn_mfma_f32_16x16x32_bf16(ahi1, bhi, accv[1][s], 0, 0, 0);
                accv[1][s] = __builtin_amdgcn_mfma_f32_16x16x32_bf16(ahi1, blo, accv[1][s], 0, 0, 0);
                accv[1][s] = __builtin_amdgcn_mfma_f32_16x16x32_bf16(alo1, bhi, accv[1][s], 0, 0, 0);
            }
        }
        __syncthreads();
    }

    // k-split reduction across the 4 waves
    #pragma unroll
    for (int mt = 0; mt < 2; ++mt)
        #pragma unroll
        for (int s = 0; s < 3; ++s)
            #pragma unroll
            for (int r = 0; r < 4; ++r) red[w][lane][(mt * 3 + s) * 4 + r] = accv[mt][s][r];
    __syncthreads();

    if (w == 0) {
        #pragma unroll
        for (int ww = 1; ww < 4; ++ww)
            #pragma unroll
            for (int mt = 0; mt < 2; ++mt)
                #pragma unroll
                for (int s = 0; s < 3; ++s)
                    #pragma unroll
                    for (int r = 0; r < 4; ++r) accv[mt][s][r] += red[ww][lane][(mt * 3 + s) * 4 + r];

        // C/D layout: col = lane&15 (j), row = q*4+reg (batch). Gate triple lives in one lane.
        int j = jb + m;
        float bh_r = b_hh[j], bh_z = b_hh[ND + j], bh_n = b_hh[2 * ND + j];
        #pragma unroll
        for (int mt = 0; mt < 2; ++mt)
            #pragma unroll
            for (int r = 0; r < 4; ++r) {
                int b = mt * 16 + q * 4 + r;
                const float* gib = GIcb + (long)idxi[b * NT + t] * NG;
                float gr = accv[mt][0][r] + bh_r;
                float gz = accv[mt][1][r] + bh_z;
                float gn = accv[mt][2][r] + bh_n;
                float rg = 1.f / (1.f + expf(-(gib[j] + gr)));
                float zg = 1.f / (1.f + expf(-(gib[ND + j] + gz)));
                float ng = tanhf(gib[2 * ND + j] + rg * gn);
                float hp = (t > 0) ? hs[(long)(b * NT + (t - 1)) * ND + j] : 0.f;
                hs[(long)(b * NT + t) * ND + j] = (1.f - zg) * ng + zg * hp;
            }
    }
}

// ---------------- CPC loss: one block per (k,l) ----------------
__global__ __launch_bounds__(256) void cp_kernel(
    const float* __restrict__ feat, const float* __restrict__ ctx,
    const int* __restrict__ perm, float* __restrict__ acc)
{
    __shared__ float cx[32][256];   // 32 KB chunk of ctx[:, l, :]
    __shared__ float red2[4];

    int tid = threadIdx.x;
    int bk = blockIdx.x;
    int kk, l;
    if (bk < 511)       { kk = 1; l = bk; }
    else if (bk < 1021) { kk = 2; l = bk - 511; }
    else                { kk = 3; l = bk - 1021; }

    float dacc[5] = {0.f, 0.f, 0.f, 0.f, 0.f};
    for (int c = 0; c < 4; ++c) {
        for (int i = 0; i < 8; ++i) {
            int g = i * 256 + tid;
            int b = g >> 6, kq = g & 63;
            *(float4*)&cx[b][kq * 4] =
                *(const float4*)(ctx + (long)(b * NT + l) * ND + c * 256 + kq * 4);
        }
        __syncthreads();
        for (int oi = 0; oi < 5; ++oi) {
            int o = tid + oi * 256;
            if (o < 1056) {
                int b = o / 33, ii = o % 33;
                const float* frow = (ii < 32)
                    ? (feat + (long)(perm[(kk - 1) * 32 + ii] * NT + l) * ND)
                    : (feat + (long)(b * NT + l + kk) * ND);
                const float4* fp4 = (const float4*)(frow + c * 256);
                const float4* cp4 = (const float4*)&cx[b][0];
                float s = 0.f;
                for (int k4 = 0; k4 < 64; ++k4) {
                    float4 cf = cp4[k4];
                    float4 ff = fp4[k4];
                    s += cf.x * ff.x + cf.y * ff.y + cf.z * ff.z + cf.w * ff.w;
                }
                dacc[oi] += s;
            }
        }
        __syncthreads();
    }

    float nsum = 0.f;
    for (int oi = 0; oi < 5; ++oi) {
        int o = tid + oi * 256;
        if (o < 1056) {
            int b = o / 33, ii = o % 33;
            float x = dacc[oi];
            if (ii < 32) {
                // stable 1 - sigmoid(x) = 1/(1+e^x): avoids fp32 saturation bias
                float sn = 1.f / (1.f + expf(x));
                nsum += -logf(sn + 1e-8f);
            } else {
                float sp = 1.f / (1.f + expf(-x));
                atomicAdd(&acc[b], -logf(sp + 1e-8f));
            }
        }
    }
    #pragma unroll
    for (int m = 1; m < 64; m <<= 1) nsum += __shfl_xor(nsum, m, 64);
    if ((tid & 63) == 0) red2[tid >> 6] = nsum;
    __syncthreads();
    if (tid == 0) atomicAdd(&acc[32], red2[0] + red2[1] + red2[2] + red2[3]);
}

// ---------------- finalize ----------------
__global__ void finalize_kernel(const float* __restrict__ acc, float* __restrict__ out) {
    int b = threadIdx.x;
    if (b < 32) {
        float cp = (acc[b] + 0.25f * acc[32] * (1.0f / 1024.0f)) * (1.0f / 1527.0f);
        float vq = 1.25f * acc[33] * (1.0f / 16777216.0f);
        out[b] = cp + vq;
    }
}

// ---------------- launch ----------------
extern "C" void kernel_launch(void* const* d_in, const int* in_sizes, int n_in,
                              void* d_out, int out_size, void* d_ws, size_t ws_size,
                              hipStream_t stream)
{
    const float* feat   = (const float*)d_in[0];
    const float* cb     = (const float*)d_in[1];
    const float* W_ih   = (const float*)d_in[2];
    const float* W_hh   = (const float*)d_in[3];
    const float* b_ih   = (const float*)d_in[4];
    const float* b_hh   = (const float*)d_in[5];
    const float* W_proj = (const float*)d_in[6];
    const float* b_proj = (const float*)d_in[7];
    const int*   nperm  = (const int*)d_in[8];

    float* outq    = (float*)d_out;                 // 16,777,216 (quantized)
    float* outidx  = outq + 16777216;               // 16,384 (indices as float)
    float* outloss = outq + 16793600;               // 32 (total_loss)

    // Workspace layout (~150 MB total; gi buffer eliminated via 256-row code table)
    char* ws = (char*)d_ws;
    float*          hs   = (float*)(ws);                        //  67,108,864 B
    float*          ctx  = (float*)(ws + 67108864);             //  67,108,864 B
    unsigned short* Whi  = (unsigned short*)(ws + 134217728);   //   6,291,456 B
    unsigned short* Wlo  = (unsigned short*)(ws + 140509184);   //   6,291,456 B
    float*          GIcb = (float*)(ws + 146800640);            //   3,145,728 B
    int*            idxi = (int*)(ws + 149946368);              //      65,536 B
    float*          acc  = (float*)(ws + 150011904);            //         256 B

    hipMemsetAsync(acc, 0, 256, stream);
    prep_w<<<12288, 256, 0, stream>>>(W_hh, Whi, Wlo);
    quantize_kernel<<<2048, 256, 0, stream>>>(feat, cb, outq, outidx, idxi, acc);
    // GIcb = codebook @ W_ih^T + b_ih   (M=256, N=3072, K=1024) — gi has only 256 distinct rows
    gemm_nt<<<dim3(24, 2), 256, 0, stream>>>(cb, W_ih, b_ih, GIcb, NG, ND);
    // sequential GRU
    for (int t = 0; t < NT; ++t)
        gru_step<<<64, 256, 0, stream>>>(hs, Whi, Wlo, GIcb, idxi, b_hh, t);
    // context_proj = hs @ W_proj^T + b_proj  (M=16384, N=1024, K=1024)
    gemm_nt<<<dim3(8, 128), 256, 0, stream>>>(hs, W_proj, b_proj, ctx, ND, ND);
    cp_kernel<<<1530, 256, 0, stream>>>(feat, ctx, nperm, acc);
    finalize_kernel<<<1, 64, 0, stream>>>(acc, outloss);
}

// Round 3
// 12297.128 us; speedup vs baseline: 1.1872x; 1.1872x over previous
//
#include <hip/hip_runtime.h>
#include <stdint.h>

// Problem constants (fixed by reference): B=32, T=512, d=1024, Kcb=256
#define NB    32
#define NT    512
#define ND    1024
#define NG    3072      // 3*d
#define NROW  16384     // B*T
#define KCB   256
#define GRU_BLOCKS 64

typedef float  f32x4 __attribute__((ext_vector_type(4)));
typedef short  s16x8 __attribute__((ext_vector_type(8)));

// ---------------- bf16 helpers (hi/lo split precision) ----------------
__device__ __forceinline__ unsigned short f32_to_bf16(float x) {
    union { float f; unsigned int u; } v; v.f = x;
    unsigned int u = v.u;
    return (unsigned short)((u + 0x7FFFu + ((u >> 16) & 1u)) >> 16);
}
__device__ __forceinline__ float bf16_to_f32(unsigned short h) {
    union { float f; unsigned int u; } v; v.u = ((unsigned int)h) << 16; return v.f;
}

// ---------------- W_hh -> bf16 hi/lo split (once per launch) ----------------
__global__ __launch_bounds__(256) void prep_w(const float* __restrict__ W,
                                              unsigned short* __restrict__ Whi,
                                              unsigned short* __restrict__ Wlo) {
    int i = blockIdx.x * 256 + threadIdx.x;   // grid sized exactly: 3072*1024/256
    float w = W[i];
    unsigned short hi = f32_to_bf16(w);
    float rem = w - bf16_to_f32(hi);
    Whi[i] = hi;
    Wlo[i] = f32_to_bf16(rem);
}

// ---------------- quantize: fp64 scores, argmin, copy row, SSD ----------------
__global__ __launch_bounds__(256) void quantize_kernel(
    const float* __restrict__ feat, const float* __restrict__ cb,
    float* __restrict__ out_q, float* __restrict__ out_idx,
    int* __restrict__ idxi, float* __restrict__ acc)
{
    __shared__ float  fr[8][1024];     // 32 KB
    __shared__ double wsco[4];
    __shared__ int    wid[4];
    __shared__ int    winner;
    __shared__ float  sp[4];

    int tid = threadIdx.x;
    int r0  = blockIdx.x * 8;

    for (int i = 0; i < 8; ++i) {
        int g   = i * 256 + tid;
        int row = g >> 8;
        int kq  = g & 255;
        float4 v = ((const float4*)(feat + (long)(r0 + row) * ND))[kq];
        ((float4*)&fr[row][0])[kq] = v;
    }
    __syncthreads();

    double dot[8];
    #pragma unroll
    for (int r = 0; r < 8; ++r) dot[r] = 0.0;
    double cc = 0.0;
    const float4* cbrow = (const float4*)(cb + (long)tid * ND);
    for (int k4 = 0; k4 < 256; ++k4) {
        float4 c = cbrow[k4];
        cc += (double)c.x * (double)c.x + (double)c.y * (double)c.y
            + (double)c.z * (double)c.z + (double)c.w * (double)c.w;
        #pragma unroll
        for (int r = 0; r < 8; ++r) {
            float4 f = ((const float4*)&fr[r][0])[k4];
            dot[r] += (double)(f.x * c.x) + (double)(f.y * c.y)
                    + (double)(f.z * c.z) + (double)(f.w * c.w);
        }
    }

    float ssd_thread = 0.f;
    for (int r = 0; r < 8; ++r) {
        double s = cc - 2.0 * dot[r];
        int idx = tid;
        #pragma unroll
        for (int m = 1; m < 64; m <<= 1) {
            double s2 = __shfl_xor(s, m, 64);
            int    i2 = __shfl_xor(idx, m, 64);
            if (s2 < s || (s2 == s && i2 < idx)) { s = s2; idx = i2; }
        }
        int w = tid >> 6;
        if ((tid & 63) == 0) { wsco[w] = s; wid[w] = idx; }
        __syncthreads();
        if (tid == 0) {
            double bs = wsco[0]; int bi = wid[0];
            for (int w2 = 1; w2 < 4; ++w2)
                if (wsco[w2] < bs || (wsco[w2] == bs && wid[w2] < bi)) { bs = wsco[w2]; bi = wid[w2]; }
            winner = bi;
            out_idx[r0 + r] = (float)bi;
            idxi[r0 + r]    = bi;
        }
        __syncthreads();
        int win = winner;
        float4 q = ((const float4*)(cb + (long)win * ND))[tid];
        ((float4*)(out_q + (long)(r0 + r) * ND))[tid] = q;
        float4 f = ((const float4*)&fr[r][0])[tid];
        float dx = f.x - q.x, dy = f.y - q.y, dz = f.z - q.z, dw = f.w - q.w;
        ssd_thread += dx * dx + dy * dy + dz * dz + dw * dw;
        __syncthreads();
    }

    #pragma unroll
    for (int m = 1; m < 64; m <<= 1) ssd_thread += __shfl_xor(ssd_thread, m, 64);
    if ((tid & 63) == 0) sp[tid >> 6] = ssd_thread;
    __syncthreads();
    if (tid == 0) atomicAdd(&acc[33], sp[0] + sp[1] + sp[2] + sp[3]);
}

// ---------------- fp32 tiled GEMM: C[M,N] = A[M,K] * W[N,K]^T + bias[N] ----------------
__global__ __launch_bounds__(256) void gemm_nt(
    const float* __restrict__ A, const float* __restrict__ W,
    const float* __restrict__ bias, float* __restrict__ C, int N, int K)
{
    __shared__ float As[16][132];
    __shared__ float Bs[16][132];
    int tid = threadIdx.x;
    int m0 = blockIdx.y * 128;
    int n0 = blockIdx.x * 128;
    int tx = tid & 15, ty = tid >> 4;

    float accum[8][8];
    #pragma unroll
    for (int i = 0; i < 8; ++i)
        #pragma unroll
        for (int j = 0; j < 8; ++j) accum[i][j] = 0.f;

    for (int k0 = 0; k0 < K; k0 += 16) {
        #pragma unroll
        for (int i = 0; i < 2; ++i) {
            int f   = tid + i * 256;
            int row = f >> 2;
            int kq  = f & 3;
            float4 a = *(const float4*)(A + (long)(m0 + row) * K + k0 + kq * 4);
            As[kq * 4 + 0][row] = a.x; As[kq * 4 + 1][row] = a.y;
            As[kq * 4 + 2][row] = a.z; As[kq * 4 + 3][row] = a.w;
            float4 b = *(const float4*)(W + (long)(n0 + row) * K + k0 + kq * 4);
            Bs[kq * 4 + 0][row] = b.x; Bs[kq * 4 + 1][row] = b.y;
            Bs[kq * 4 + 2][row] = b.z; Bs[kq * 4 + 3][row] = b.w;
        }
        __syncthreads();
        #pragma unroll
        for (int kk = 0; kk < 16; ++kk) {
            float4 a01 = *(const float4*)&As[kk][ty * 8];
            float4 a23 = *(const float4*)&As[kk][ty * 8 + 4];
            float4 b01 = *(const float4*)&Bs[kk][tx * 8];
            float4 b23 = *(const float4*)&Bs[kk][tx * 8 + 4];
            float av[8] = {a01.x, a01.y, a01.z, a01.w, a23.x, a23.y, a23.z, a23.w};
            float bv[8] = {b01.x, b01.y, b01.z, b01.w, b23.x, b23.y, b23.z, b23.w};
            #pragma unroll
            for (int i = 0; i < 8; ++i)
                #pragma unroll
                for (int j = 0; j < 8; ++j) accum[i][j] += av[i] * bv[j];
        }
        __syncthreads();
    }
    #pragma unroll
    for (int i = 0; i < 8; ++i) {
        float* crow = C + (long)(m0 + ty * 8 + i) * N + n0 + tx * 8;
        const float* brow = bias + n0 + tx * 8;
        float4 o0, o1;
        o0.x = accum[i][0] + brow[0]; o0.y = accum[i][1] + brow[1];
        o0.z = accum[i][2] + brow[2]; o0.w = accum[i][3] + brow[3];
        o1.x = accum[i][4] + brow[4]; o1.y = accum[i][5] + brow[5];
        o1.z = accum[i][6] + brow[6]; o1.w = accum[i][7] + brow[7];
        *(float4*)(crow)     = o0;
        *(float4*)(crow + 4) = o1;
    }
}

// ---------------- persistent GRU: 1 launch, 512 steps, grid barrier per step ----------------
// 64 blocks x 256 thr. Same MFMA hi/lo math as the verified per-step kernel; h handed
// between steps as bf16 hi/lo via double-buffered global hbf (written by epilogue).
__device__ __forceinline__ void grid_barrier(int* bar, int step) {
    __threadfence();                         // release this thread's writes (agent scope)
    __syncthreads();
    if (threadIdx.x == 0) {
        int target = GRU_BLOCKS * (step + 1);
        __hip_atomic_fetch_add(bar, 1, __ATOMIC_ACQ_REL, __HIP_MEMORY_SCOPE_AGENT);
        while (__hip_atomic_load(bar, __ATOMIC_ACQUIRE, __HIP_MEMORY_SCOPE_AGENT) < target)
            __builtin_amdgcn_s_sleep(1);
    }
    __syncthreads();
    __threadfence();                         // acquire
}

__global__ __launch_bounds__(256) void gru_persist(
    float* hs,
    const unsigned short* __restrict__ Whi, const unsigned short* __restrict__ Wlo,
    const float* __restrict__ GIcb, const int* __restrict__ idxi,
    const float* __restrict__ b_hh,
    unsigned short* hbf,                    // [2 bufs][hi/lo][32][1024]
    int* bar)
{
    __shared__ unsigned short hhi[32][264];
    __shared__ unsigned short hlo[32][264];
    __shared__ float red[4][64][25];

    int tid  = threadIdx.x;
    int lane = tid & 63;
    int w    = tid >> 6;
    int jb   = blockIdx.x * 16;
    int m    = lane & 15, q = lane >> 4;

    // epilogue mapping: thread -> (j = tid&15, eb = tid>>4), outputs b = eb and eb+16
    int ej = tid & 15;
    int eb = tid >> 4;
    int eq = eb >> 2, er = eb & 3;
    int j  = jb + ej;
    float bh_r = b_hh[j], bh_z = b_hh[ND + j], bh_n = b_hh[2 * ND + j];

    #pragma unroll 1
    for (int t = 0; t < NT; ++t) {
        int rb = (t + 1) & 1;               // buffer written last step
        int wb = t & 1;
        const unsigned short* rhi = hbf + (rb * 2 + 0) * 32768;
        const unsigned short* rlo = hbf + (rb * 2 + 1) * 32768;
        unsigned short*       whi_ = hbf + (wb * 2 + 0) * 32768;
        unsigned short*       wlo_ = hbf + (wb * 2 + 1) * 32768;

        f32x4 accv[2][3];
        #pragma unroll
        for (int mt = 0; mt < 2; ++mt)
            #pragma unroll
            for (int s = 0; s < 3; ++s) accv[mt][s] = (f32x4){0.f, 0.f, 0.f, 0.f};

        for (int c = 0; c < 4; ++c) {
            // stage h chunk (bf16 hi/lo, ushort8 vector loads; t==0 -> zeros)
            #pragma unroll
            for (int i = 0; i < 4; ++i) {
                int g = i * 256 + tid;      // 1024 ushort8 per part per chunk
                int b = g >> 5, k8 = g & 31;
                s16x8 vh, vl;
                if (t > 0) {
                    vh = *(const s16x8*)(rhi + (long)b * ND + c * 256 + k8 * 8);
                    vl = *(const s16x8*)(rlo + (long)b * ND + c * 256 + k8 * 8);
                } else {
                    vh = (s16x8){0,0,0,0,0,0,0,0};
                    vl = (s16x8){0,0,0,0,0,0,0,0};
                }
                *(s16x8*)&hhi[b][k8 * 8] = vh;
                *(s16x8*)&hlo[b][k8 * 8] = vl;
            }
            __syncthreads();
            #pragma unroll
            for (int kkl = 0; kkl < 2; ++kkl) {
                int kk    = w * 2 + kkl;
                int koff  = kk * 32 + q * 8;
                int kglob = c * 256 + koff;
                s16x8 ahi0 = *(const s16x8*)&hhi[m][koff];
                s16x8 alo0 = *(const s16x8*)&hlo[m][koff];
                s16x8 ahi1 = *(const s16x8*)&hhi[m + 16][koff];
                s16x8 alo1 = *(const s16x8*)&hlo[m + 16][koff];
                #pragma unroll
                for (int s = 0; s < 3; ++s) {
                    long wrow = (long)(s * ND + jb + m) * ND + kglob;
                    s16x8 bhi = *(const s16x8*)(Whi + wrow);
                    s16x8 blo = *(const s16x8*)(Wlo + wrow);
                    accv[0][s] = __builtin_amdgcn_mfma_f32_16x16x32_bf16(ahi0, bhi, accv[0][s], 0, 0, 0);
                    accv[0][s] = __builtin_amdgcn_mfma_f32_16x16x32_bf16(ahi0, blo, accv[0][s], 0, 0, 0);
                    accv[0][s] = __builtin_amdgcn_mfma_f32_16x16x32_bf16(alo0, bhi, accv[0][s], 0, 0, 0);
                    accv[1][s] = __builtin_amdgcn_mfma_f32_16x16x32_bf16(ahi1, bhi, accv[1][s], 0, 0, 0);
                    accv[1][s] = __builtin_amdgcn_mfma_f32_16x16x32_bf16(ahi1, blo, accv[1][s], 0, 0, 0);
                    accv[1][s] = __builtin_amdgcn_mfma_f32_16x16x32_bf16(alo1, bhi, accv[1][s], 0, 0, 0);
                }
            }
            __syncthreads();
        }

        // k-split partials -> LDS
        #pragma unroll
        for (int mt = 0; mt < 2; ++mt)
            #pragma unroll
            for (int s = 0; s < 3; ++s)
                #pragma unroll
                for (int r = 0; r < 4; ++r) red[w][lane][(mt * 3 + s) * 4 + r] = accv[mt][s][r];
        __syncthreads();

        // epilogue: all 256 threads, 2 outputs each (b=eb, eb+16 at column j)
        #pragma unroll
        for (int mt = 0; mt < 2; ++mt) {
            int b = mt * 16 + eb;
            int sl = eq * 16 + ej;
            float g0 = 0.f, g1 = 0.f, g2 = 0.f;
            #pragma unroll
            for (int ww = 0; ww < 4; ++ww) {
                g0 += red[ww][sl][(mt * 3 + 0) * 4 + er];
                g1 += red[ww][sl][(mt * 3 + 1) * 4 + er];
                g2 += red[ww][sl][(mt * 3 + 2) * 4 + er];
            }
            const float* gib = GIcb + (long)idxi[b * NT + t] * NG;
            float xr = gib[j]          + g0 + bh_r;
            float xz = gib[ND + j]     + g1 + bh_z;
            float xn = gib[2 * ND + j] + g2 + bh_n;
            float rg = 1.f / (1.f + __expf(-xr));
            float zg = 1.f / (1.f + __expf(-xz));
            float a  = xn + rg * g2 * 0.f + rg * 0.f;  // placeholder avoided below
            (void)a;
            float narg = xn + 0.f;                     // n pre-activation: i_n + r*h_n
            // NOTE: reference: n = tanh(i_n + r*(Whh_n·h + b_hh_n)); g2+bh_n IS (Whh_n·h+b_hh_n)
            narg = gib[2 * ND + j] + rg * (g2 + bh_n);
            float e2 = __expf(2.f * narg);
            float ng = 1.f - 2.f / (e2 + 1.f);
            float hp = (t > 0) ? hs[(long)(b * NT + (t - 1)) * ND + j] : 0.f;
            float hn = (1.f - zg) * ng + zg * hp;
            hs[(long)(b * NT + t) * ND + j] = hn;
            unsigned short hh16 = f32_to_bf16(hn);
            whi_[b * ND + j] = hh16;
            wlo_[b * ND + j] = f32_to_bf16(hn - bf16_to_f32(hh16));
        }

        grid_barrier(bar, t);
    }
}

// ---------------- CPC loss: one block per (k,l) ----------------
__global__ __launch_bounds__(256) void cp_kernel(
    const float* __restrict__ feat, const float* __restrict__ ctx,
    const int* __restrict__ perm, float* __restrict__ acc)
{
    __shared__ float cx[32][256];
    __shared__ float red2[4];

    int tid = threadIdx.x;
    int bk = blockIdx.x;
    int kk, l;
    if (bk < 511)       { kk = 1; l = bk; }
    else if (bk < 1021) { kk = 2; l = bk - 511; }
    else                { kk = 3; l = bk - 1021; }

    float dacc[5] = {0.f, 0.f, 0.f, 0.f, 0.f};
    for (int c = 0; c < 4; ++c) {
        for (int i = 0; i < 8; ++i) {
            int g = i * 256 + tid;
            int b = g >> 6, kq = g & 63;
            *(float4*)&cx[b][kq * 4] =
                *(const float4*)(ctx + (long)(b * NT + l) * ND + c * 256 + kq * 4);
        }
        __syncthreads();
        for (int oi = 0; oi < 5; ++oi) {
            int o = tid + oi * 256;
            if (o < 1056) {
                int b = o / 33, ii = o % 33;
                const float* frow = (ii < 32)
                    ? (feat + (long)(perm[(kk - 1) * 32 + ii] * NT + l) * ND)
                    : (feat + (long)(b * NT + l + kk) * ND);
                const float4* fp4 = (const float4*)(frow + c * 256);
                const float4* cp4 = (const float4*)&cx[b][0];
                float s = 0.f;
                for (int k4 = 0; k4 < 64; ++k4) {
                    float4 cf = cp4[k4];
                    float4 ff = fp4[k4];
                    s += cf.x * ff.x + cf.y * ff.y + cf.z * ff.z + cf.w * ff.w;
                }
                dacc[oi] += s;
            }
        }
        __syncthreads();
    }

    float nsum = 0.f;
    for (int oi = 0; oi < 5; ++oi) {
        int o = tid + oi * 256;
        if (o < 1056) {
            int b = o / 33, ii = o % 33;
            float x = dacc[oi];
            if (ii < 32) {
                float sn = 1.f / (1.f + expf(x));
                nsum += -logf(sn + 1e-8f);
            } else {
                float sp = 1.f / (1.f + expf(-x));
                atomicAdd(&acc[b], -logf(sp + 1e-8f));
            }
        }
    }
    #pragma unroll
    for (int m = 1; m < 64; m <<= 1) nsum += __shfl_xor(nsum, m, 64);
    if ((tid & 63) == 0) red2[tid >> 6] = nsum;
    __syncthreads();
    if (tid == 0) atomicAdd(&acc[32], red2[0] + red2[1] + red2[2] + red2[3]);
}

// ---------------- finalize ----------------
__global__ void finalize_kernel(const float* __restrict__ acc, float* __restrict__ out) {
    int b = threadIdx.x;
    if (b < 32) {
        float cp = (acc[b] + 0.25f * acc[32] * (1.0f / 1024.0f)) * (1.0f / 1527.0f);
        float vq = 1.25f * acc[33] * (1.0f / 16777216.0f);
        out[b] = cp + vq;
    }
}

// ---------------- launch ----------------
extern "C" void kernel_launch(void* const* d_in, const int* in_sizes, int n_in,
                              void* d_out, int out_size, void* d_ws, size_t ws_size,
                              hipStream_t stream)
{
    const float* feat   = (const float*)d_in[0];
    const float* cb     = (const float*)d_in[1];
    const float* W_ih   = (const float*)d_in[2];
    const float* W_hh   = (const float*)d_in[3];
    const float* b_ih   = (const float*)d_in[4];
    const float* b_hh   = (const float*)d_in[5];
    const float* W_proj = (const float*)d_in[6];
    const float* b_proj = (const float*)d_in[7];
    const int*   nperm  = (const int*)d_in[8];

    float* outq    = (float*)d_out;
    float* outidx  = outq + 16777216;
    float* outloss = outq + 16793600;

    char* ws = (char*)d_ws;
    float*          hs   = (float*)(ws);                        //  67,108,864 B
    float*          ctx  = (float*)(ws + 67108864);             //  67,108,864 B
    unsigned short* Whi  = (unsigned short*)(ws + 134217728);   //   6,291,456 B
    unsigned short* Wlo  = (unsigned short*)(ws + 140509184);   //   6,291,456 B
    float*          GIcb = (float*)(ws + 146800640);            //   3,145,728 B
    int*            idxi = (int*)(ws + 149946368);              //      65,536 B
    float*          acc  = (float*)(ws + 150011904);            //  256 B acc + 256 B bar
    int*            bar  = (int*)(ws + 150012160);
    unsigned short* hbf  = (unsigned short*)(ws + 150012416);   //     262,144 B

    hipMemsetAsync(acc, 0, 512, stream);   // zeroes acc[0..63] AND bar
    prep_w<<<12288, 256, 0, stream>>>(W_hh, Whi, Wlo);
    quantize_kernel<<<2048, 256, 0, stream>>>(feat, cb, outq, outidx, idxi, acc);
    // GIcb = codebook @ W_ih^T + b_ih  (256x3072, K=1024)
    gemm_nt<<<dim3(24, 2), 256, 0, stream>>>(cb, W_ih, b_ih, GIcb, NG, ND);
    // persistent GRU: one launch, 512 in-kernel steps
    gru_persist<<<GRU_BLOCKS, 256, 0, stream>>>(hs, Whi, Wlo, GIcb, idxi, b_hh, hbf, bar);
    // context_proj = hs @ W_proj^T + b_proj
    gemm_nt<<<dim3(8, 128), 256, 0, stream>>>(hs, W_proj, b_proj, ctx, ND, ND);
    cp_kernel<<<1530, 256, 0, stream>>>(feat, ctx, nperm, acc);
    finalize_kernel<<<1, 64, 0, stream>>>(acc, outloss);
}